// Round 1
// baseline (1356.839 us; speedup 1.0000x reference)
//
#include <hip/hip_runtime.h>
#include <math.h>

#define T_LEN 1024
#define D_MODEL 1024
#define NQH 16
#define NKV 4
#define REP 4
#define DH 64
#define NB 63          // number of compressed blocks
#define TOPN 8
#define KVD 256        // NKV*DH

__device__ __forceinline__ float gelu_exact(float x) {
    return 0.5f * x * (1.0f + erff(x * 0.70710678118654752f));
}

__device__ __forceinline__ float sigmoidf(float x) {
    return 1.0f / (1.0f + expf(-x));
}

// ---------------------------------------------------------------------------
// C[M,N] = A[M,K] @ B[N,K]^T + bias[N]   (A row-major MxK, B row-major NxK)
// 64x64 tile, 4x4 per-thread microtile, BK=16.
// ---------------------------------------------------------------------------
__global__ __launch_bounds__(256) void gemm_nt(const float* __restrict__ A,
                                               const float* __restrict__ B,
                                               const float* __restrict__ bias,
                                               float* __restrict__ C,
                                               int M, int N, int K) {
    __shared__ float As[16][65];
    __shared__ float Bs[16][65];
    const int tid = threadIdx.x;
    const int tx = tid & 15, ty = tid >> 4;
    const int m0 = blockIdx.y * 64, n0 = blockIdx.x * 64;
    float acc[4][4] = {};
    for (int k0 = 0; k0 < K; k0 += 16) {
        for (int e = tid; e < 64 * 16; e += 256) {
            int row = e >> 4, col = e & 15;
            int m = m0 + row;
            As[col][row] = (m < M) ? A[m * K + k0 + col] : 0.0f;
        }
        for (int e = tid; e < 64 * 16; e += 256) {
            int row = e >> 4, col = e & 15;
            int n = n0 + row;
            Bs[col][row] = (n < N) ? B[n * K + k0 + col] : 0.0f;
        }
        __syncthreads();
        #pragma unroll
        for (int kk = 0; kk < 16; ++kk) {
            float a[4], b[4];
            #pragma unroll
            for (int i = 0; i < 4; ++i) a[i] = As[kk][ty * 4 + i];
            #pragma unroll
            for (int j = 0; j < 4; ++j) b[j] = Bs[kk][tx * 4 + j];
            #pragma unroll
            for (int i = 0; i < 4; ++i)
                #pragma unroll
                for (int j = 0; j < 4; ++j) acc[i][j] += a[i] * b[j];
        }
        __syncthreads();
    }
    for (int i = 0; i < 4; ++i) {
        int m = m0 + ty * 4 + i;
        if (m >= M) continue;
        for (int j = 0; j < 4; ++j) {
            int n = n0 + tx * 4 + j;
            if (n < N) C[m * N + n] = acc[i][j] + (bias ? bias[n] : 0.0f);
        }
    }
}

// ---------------------------------------------------------------------------
// Compressed block summaries: for each (block n, kv head k, {k,v}):
//   flat[2048] = kv[start+p, k, d] + block_pos[p, d]   (i = p*64 + d)
//   hidden[64] = gelu(flat @ w1^T + b1)
//   out[64]    = hidden @ w2^T + b2
// grid (63, 4, 2), 256 threads
// ---------------------------------------------------------------------------
__global__ __launch_bounds__(256) void nsa_summarize(
    const float* __restrict__ k_cmp, const float* __restrict__ v_cmp,
    const float* __restrict__ block_pos,
    const float* __restrict__ ck1_w, const float* __restrict__ ck1_b,
    const float* __restrict__ ck2_w, const float* __restrict__ ck2_b,
    const float* __restrict__ cv1_w, const float* __restrict__ cv1_b,
    const float* __restrict__ cv2_w, const float* __restrict__ cv2_b,
    float* __restrict__ ksum, float* __restrict__ vsum)
{
    const int n = blockIdx.x, k = blockIdx.y, which = blockIdx.z;
    const float* src = which ? v_cmp : k_cmp;
    const float* w1  = which ? cv1_w : ck1_w;
    const float* b1  = which ? cv1_b : ck1_b;
    const float* w2  = which ? cv2_w : ck2_w;
    const float* b2  = which ? cv2_b : ck2_b;
    float* dst       = which ? vsum  : ksum;

    __shared__ float flat[32 * DH];   // 2048
    __shared__ float hidden[DH];
    const int tid = threadIdx.x;
    const int start = n * 16;

    for (int e = tid; e < 32 * DH; e += 256) {
        int p = e >> 6, d = e & 63;
        flat[e] = src[((start + p) * NKV + k) * DH + d] + block_pos[p * DH + d];
    }
    __syncthreads();
    {
        int h = tid >> 2, part = tid & 3;
        const float* wr = w1 + h * 2048;
        float s = 0.0f;
        int j0 = part * 512;
        for (int j = j0; j < j0 + 512; ++j) s += flat[j] * wr[j];
        s += __shfl_xor(s, 1);
        s += __shfl_xor(s, 2);
        if (part == 0) hidden[h] = gelu_exact(s + b1[h]);
    }
    __syncthreads();
    {
        int dh = tid >> 2, part = tid & 3;
        const float* wr = w2 + dh * 64;
        float s = 0.0f;
        int h0 = part * 16;
        for (int hh = h0; hh < h0 + 16; ++hh) s += hidden[hh] * wr[hh];
        s += __shfl_xor(s, 1);
        s += __shfl_xor(s, 2);
        if (part == 0) dst[(n * NKV + k) * DH + dh] = s + b2[dh];
    }
}

// ---------------------------------------------------------------------------
// Fused attention: one workgroup per (t, kv head k); wave r handles GQA rep r.
// Does: compressed attn + top-8 selection + selected attn + window attn + gate.
// ---------------------------------------------------------------------------
__global__ __launch_bounds__(256) void nsa_fused(
    const float* __restrict__ q,         // (16, T, 64)
    const float* __restrict__ gates_lin, // (T, 48)  pre-sigmoid
    const float* __restrict__ ksum,      // (63, 4, 64)
    const float* __restrict__ vsum,
    const float* __restrict__ k_slc,     // (T, 4, 64)
    const float* __restrict__ v_slc,
    const float* __restrict__ k_win,
    const float* __restrict__ v_win,
    float* __restrict__ out)             // (16, T, 64)
{
    const int t = blockIdx.x;
    const int k = blockIdx.y;
    const int tid = threadIdx.x;
    const int lane = tid & 63;
    const int r = tid >> 6;

    __shared__ float q_s[REP][DH];
    __shared__ float p_cmp_s[REP][64];
    __shared__ float sc_s[REP][256];
    __shared__ float chunk[64][DH + 1];
    __shared__ int   sel_s[TOPN];

    // ---- load q ----
    q_s[r][lane] = q[((r * NKV + k) * T_LEN + t) * DH + lane];
    __syncthreads();

    // ---- compressed scores: lane = block index n ----
    float s = -1e30f;
    if (lane < NB) {
        bool vis = (lane * 16 + 31) <= t;
        if (vis) {
            float acc = 0.0f;
            const float* kr = ksum + (lane * NKV + k) * DH;
            #pragma unroll 16
            for (int d = 0; d < DH; ++d) acc += q_s[r][d] * kr[d];
            s = acc * 0.125f;
        }
    }
    // wave softmax over the 63 real entries (lane 63 excluded via e=0)
    float m = s;
    for (int off = 32; off; off >>= 1) m = fmaxf(m, __shfl_xor(m, off));
    float e = (lane < NB) ? expf(s - m) : 0.0f;
    float sum = e;
    for (int off = 32; off; off >>= 1) sum += __shfl_xor(sum, off);
    float p = e / sum;
    p_cmp_s[r][lane] = (lane < NB) ? p : 0.0f;
    __syncthreads();

    // ---- out_cmp: lane = d ----
    float ocmp = 0.0f;
    if (t >= 31) {  // vis.any over blocks
        for (int n = 0; n < NB; ++n)
            ocmp += p_cmp_s[r][n] * vsum[(n * NKV + k) * DH + lane];
    }

    // ---- top-8 selection on imp = sum_r p_cmp (wave 0), stable ties ----
    if (r == 0) {
        float imp = (lane < NB)
            ? (p_cmp_s[0][lane] + p_cmp_s[1][lane] + p_cmp_s[2][lane] + p_cmp_s[3][lane])
            : -1e30f;
        const int idx = lane;
        for (int it = 0; it < TOPN; ++it) {
            float v = imp; int i = idx;
            for (int off = 32; off; off >>= 1) {
                float ov = __shfl_xor(v, off);
                int   oi = __shfl_xor(i, off);
                if (ov > v || (ov == v && oi < i)) { v = ov; i = oi; }
            }
            if (lane == 0) sel_s[it] = i;
            if (lane == i) imp = -1e30f;
        }
    }
    __syncthreads();

    // ---- selected branch: S = 8 blocks * 32 = 256 positions ----
    float oslc = 0.0f;
    for (int c = 0; c < 4; ++c) {
        __syncthreads();
        for (int e2 = tid; e2 < 64 * DH; e2 += 256) {
            int pidx = e2 >> 6, d = e2 & 63;
            int j = c * 64 + pidx;
            int pos = sel_s[j >> 5] * 16 + (j & 31);
            chunk[pidx][d] = k_slc[(pos * NKV + k) * DH + d];
        }
        __syncthreads();
        int j = c * 64 + lane;
        int pos = sel_s[j >> 5] * 16 + (j & 31);
        float acc = 0.0f;
        #pragma unroll 16
        for (int d = 0; d < DH; ++d) acc += q_s[r][d] * chunk[lane][d];
        sc_s[r][j] = (pos <= t) ? acc * 0.125f : -1e30f;
    }
    __syncthreads();
    {   // per-rep softmax over 256 (4 values per lane)
        float v0 = sc_s[r][lane], v1 = sc_s[r][64 + lane];
        float v2 = sc_s[r][128 + lane], v3 = sc_s[r][192 + lane];
        float mx = fmaxf(fmaxf(v0, v1), fmaxf(v2, v3));
        for (int off = 32; off; off >>= 1) mx = fmaxf(mx, __shfl_xor(mx, off));
        float e0 = expf(v0 - mx), e1 = expf(v1 - mx), e2 = expf(v2 - mx), e3 = expf(v3 - mx);
        float sm = e0 + e1 + e2 + e3;
        for (int off = 32; off; off >>= 1) sm += __shfl_xor(sm, off);
        float inv = 1.0f / sm;
        sc_s[r][lane] = e0 * inv; sc_s[r][64 + lane] = e1 * inv;
        sc_s[r][128 + lane] = e2 * inv; sc_s[r][192 + lane] = e3 * inv;
    }
    for (int c = 0; c < 4; ++c) {
        __syncthreads();
        for (int e2 = tid; e2 < 64 * DH; e2 += 256) {
            int pidx = e2 >> 6, d = e2 & 63;
            int j = c * 64 + pidx;
            int pos = sel_s[j >> 5] * 16 + (j & 31);
            chunk[pidx][d] = v_slc[(pos * NKV + k) * DH + d];
        }
        __syncthreads();
        #pragma unroll 8
        for (int pidx = 0; pidx < 64; ++pidx)
            oslc += sc_s[r][c * 64 + pidx] * chunk[pidx][lane];
    }

    // ---- sliding-window branch: positions j0..t, W = t-j0+1 <= 256 ----
    float owin = 0.0f;
    const int j0 = (t >= 255) ? (t - 255) : 0;
    const int W = t - j0 + 1;
    for (int c = 0; c < 4; ++c) {
        __syncthreads();
        for (int e2 = tid; e2 < 64 * DH; e2 += 256) {
            int pidx = e2 >> 6, d = e2 & 63;
            int pos = j0 + c * 64 + pidx;   // always < T
            chunk[pidx][d] = k_win[(pos * NKV + k) * DH + d];
        }
        __syncthreads();
        int jj = c * 64 + lane;
        float acc = 0.0f;
        #pragma unroll 16
        for (int d = 0; d < DH; ++d) acc += q_s[r][d] * chunk[lane][d];
        sc_s[r][jj] = (jj < W) ? acc * 0.125f : -1e30f;
    }
    __syncthreads();
    {
        float v0 = sc_s[r][lane], v1 = sc_s[r][64 + lane];
        float v2 = sc_s[r][128 + lane], v3 = sc_s[r][192 + lane];
        float mx = fmaxf(fmaxf(v0, v1), fmaxf(v2, v3));
        for (int off = 32; off; off >>= 1) mx = fmaxf(mx, __shfl_xor(mx, off));
        float e0 = expf(v0 - mx), e1 = expf(v1 - mx), e2 = expf(v2 - mx), e3 = expf(v3 - mx);
        float sm = e0 + e1 + e2 + e3;
        for (int off = 32; off; off >>= 1) sm += __shfl_xor(sm, off);
        float inv = 1.0f / sm;
        sc_s[r][lane] = e0 * inv; sc_s[r][64 + lane] = e1 * inv;
        sc_s[r][128 + lane] = e2 * inv; sc_s[r][192 + lane] = e3 * inv;
    }
    for (int c = 0; c < 4; ++c) {
        __syncthreads();
        for (int e2 = tid; e2 < 64 * DH; e2 += 256) {
            int pidx = e2 >> 6, d = e2 & 63;
            int pos = j0 + c * 64 + pidx;
            chunk[pidx][d] = v_win[(pos * NKV + k) * DH + d];
        }
        __syncthreads();
        #pragma unroll 8
        for (int pidx = 0; pidx < 64; ++pidx)
            owin += sc_s[r][c * 64 + pidx] * chunk[pidx][lane];
    }

    // ---- gating + write (lane = d) ----
    const int hq = r * NKV + k;
    const float* gl = gates_lin + t * 48 + hq * 3;
    float g0 = sigmoidf(gl[0]);
    float g1 = sigmoidf(gl[1]);
    float g2 = sigmoidf(gl[2]);
    out[(hq * T_LEN + t) * DH + lane] = g0 * ocmp + g1 * oslc + g2 * owin;
}

extern "C" void kernel_launch(void* const* d_in, const int* in_sizes, int n_in,
                              void* d_out, int out_size, void* d_ws, size_t ws_size,
                              hipStream_t stream) {
    const float* x         = (const float*)d_in[0];
    const float* q         = (const float*)d_in[1];
    const float* gate_w    = (const float*)d_in[2];
    const float* gate_b    = (const float*)d_in[3];
    const float* wk_cmp    = (const float*)d_in[4];
    const float* wv_cmp    = (const float*)d_in[5];
    const float* wk_slc    = (const float*)d_in[6];
    const float* wv_slc    = (const float*)d_in[7];
    const float* wk_win    = (const float*)d_in[8];
    const float* wv_win    = (const float*)d_in[9];
    const float* block_pos = (const float*)d_in[10];
    const float* ck1_w     = (const float*)d_in[11];
    const float* ck1_b     = (const float*)d_in[12];
    const float* ck2_w     = (const float*)d_in[13];
    const float* ck2_b     = (const float*)d_in[14];
    const float* cv1_w     = (const float*)d_in[15];
    const float* cv1_b     = (const float*)d_in[16];
    const float* cv2_w     = (const float*)d_in[17];
    const float* cv2_b     = (const float*)d_in[18];
    float* out = (float*)d_out;

    float* ws = (float*)d_ws;
    float* gates_lin = ws;                         // 1024*48   = 49152
    float* k_cmp = gates_lin + T_LEN * 48;         // 1024*256  = 262144 each
    float* v_cmp = k_cmp + T_LEN * KVD;
    float* k_slc = v_cmp + T_LEN * KVD;
    float* v_slc = k_slc + T_LEN * KVD;
    float* k_win = v_slc + T_LEN * KVD;
    float* v_win = k_win + T_LEN * KVD;
    float* ksum  = v_win + T_LEN * KVD;            // 63*4*64 = 16128 each
    float* vsum  = ksum + NB * KVD;

    dim3 blk(256);
    // projections
    gemm_nt<<<dim3(1, 16), blk, 0, stream>>>(x, gate_w, gate_b, gates_lin, T_LEN, 48, D_MODEL);
    gemm_nt<<<dim3(4, 16), blk, 0, stream>>>(x, wk_cmp, nullptr, k_cmp, T_LEN, KVD, D_MODEL);
    gemm_nt<<<dim3(4, 16), blk, 0, stream>>>(x, wv_cmp, nullptr, v_cmp, T_LEN, KVD, D_MODEL);
    gemm_nt<<<dim3(4, 16), blk, 0, stream>>>(x, wk_slc, nullptr, k_slc, T_LEN, KVD, D_MODEL);
    gemm_nt<<<dim3(4, 16), blk, 0, stream>>>(x, wv_slc, nullptr, v_slc, T_LEN, KVD, D_MODEL);
    gemm_nt<<<dim3(4, 16), blk, 0, stream>>>(x, wk_win, nullptr, k_win, T_LEN, KVD, D_MODEL);
    gemm_nt<<<dim3(4, 16), blk, 0, stream>>>(x, wv_win, nullptr, v_win, T_LEN, KVD, D_MODEL);
    // block summaries
    nsa_summarize<<<dim3(NB, NKV, 2), blk, 0, stream>>>(
        k_cmp, v_cmp, block_pos,
        ck1_w, ck1_b, ck2_w, ck2_b, cv1_w, cv1_b, cv2_w, cv2_b,
        ksum, vsum);
    // fused attention + gating
    nsa_fused<<<dim3(T_LEN, NKV), blk, 0, stream>>>(
        q, gates_lin, ksum, vsum, k_slc, v_slc, k_win, v_win, out);
}